// Round 12
// baseline (3973.087 us; speedup 1.0000x reference)
//
#include <hip/hip_runtime.h>
#include <hip/hip_bf16.h>
#include <hip/hip_fp16.h>

#define TT 2048
#define BB 16
#define DD 256
#define GG 1024   // 4U
#define UU 256

using f32x4  = __attribute__((ext_vector_type(4))) float;
using short8 = __attribute__((ext_vector_type(8))) short;
using f16x8  = __attribute__((ext_vector_type(8))) _Float16;
using u32x4  = __attribute__((ext_vector_type(4))) unsigned int;

static __device__ __forceinline__ unsigned short f2h_u(float f){
  _Float16 h = (_Float16)f;
  return __builtin_bit_cast(unsigned short, h);
}
static __device__ __forceinline__ float h2f(unsigned short u){
  return (float)__builtin_bit_cast(_Float16, u);
}
static __device__ __forceinline__ unsigned short f2bf_u(float f){
  __hip_bfloat16 b = __float2bfloat16(f);
  return __builtin_bit_cast(unsigned short, b);
}
static __device__ __forceinline__ float sigmoid_f(float x){
  return 1.0f / (1.0f + __expf(-x));
}
static __device__ __forceinline__ float tanh_f(float x){
  float ax = fabsf(x);
  float e  = __expf(2.0f*ax);          // overflow -> inf is fine: r -> 1
  float r  = 1.0f - 2.0f/(e + 1.0f);
  return copysignf(r, x);
}
static __device__ __forceinline__ f32x4 mfma16x16x32_f16(f16x8 a, f16x8 b, f32x4 c){
  return __builtin_amdgcn_mfma_f32_16x16x32_f16(a, b, c, 0, 0, 0);
}
// raw workgroup barrier ordering LDS only (no vmcnt drain)
static __device__ __forceinline__ void lds_barrier(){
  __builtin_amdgcn_sched_barrier(0);
  asm volatile("s_waitcnt lgkmcnt(0)" ::: "memory");
  __builtin_amdgcn_s_barrier();
  __builtin_amdgcn_sched_barrier(0);
}

// ---- converts -------------------------------------------------------------
__global__ __launch_bounds__(256) void cvt_x_kernel(const float* __restrict__ x,
                                                    unsigned short* __restrict__ xh){
  int gid = blockIdx.x*256 + threadIdx.x;
  const float4* xv = (const float4*)x;
  float4 v = xv[gid];
  unsigned int u0 = (unsigned int)f2bf_u(v.x) | ((unsigned int)f2bf_u(v.y) << 16);
  unsigned int u1 = (unsigned int)f2bf_u(v.z) | ((unsigned int)f2bf_u(v.w) << 16);
  ((uint2*)xh)[gid] = make_uint2(u0, u1);
}

// W [256][1024] f32 -> W^T bf16 [dir][1024][256]
__global__ __launch_bounds__(256) void cvt_wt_kernel(const float* __restrict__ Wf,
                                                     const float* __restrict__ Wb,
                                                     unsigned short* __restrict__ wt){
  int gid = blockIdx.x*256 + threadIdx.x;
  int d   = gid >> 18;
  int rem = gid & 262143;
  int n   = rem >> 8;
  int k   = rem & 255;
  const float* src = d ? Wb : Wf;
  wt[gid] = f2bf_u(src[k*GG + n]);
}

// R [256][1024] f32 -> A-fragment-ready f16, col-order [block Q][unit][gate],
// k-permuted to match the scan's h^T B-fragment assembly:
//   storage pos p (0..255): s=p>>5, l4=(p>>3)&3, e=p&7
//   k = 32s + (e<4 ? 4*l4+e : 16 + 4*l4 + (e-4))
__global__ __launch_bounds__(256) void cvt_rt_kernel(const float* __restrict__ Rf,
                                                     const float* __restrict__ Rb,
                                                     unsigned short* __restrict__ rt){
  int gid = blockIdx.x*256 + threadIdx.x;           // 2*1024*256
  int d   = gid >> 18;
  int rem = gid & 262143;
  int c   = rem >> 8;                               // storage col 0..1023
  int p   = rem & 255;                              // k-position
  int Qb  = c >> 7, tc = c & 127;
  int ul  = tc >> 2, g = tc & 3;
  int ucol = g*256 + Qb*32 + ul;                    // source col in R[256][1024]
  int s = p >> 5, l4g = (p >> 3) & 3, e = p & 7;
  int k = 32*s + (e < 4 ? 4*l4g + e : 16 + 4*l4g + (e - 4));
  const float* src = d ? Rb : Rf;
  rt[gid] = f2h_u(src[k*GG + ucol]);
}

// ---- proj GEMM: M-tile = 16 batches x 8 timesteps; writes projT[t][col][16b]
__global__ __launch_bounds__(256) void gemm_projT(const unsigned short* __restrict__ Ah,
                                                  const unsigned short* __restrict__ BTh,
                                                  unsigned short* __restrict__ Cd,
                                                  int xstart, int Tc){
  __shared__ __align__(16) unsigned short smem[18432];
  unsigned short* sA = smem;             // [128][72]
  unsigned short* sB = smem + 9216;      // [128][72]
  unsigned short* sC = smem;             // [128][136]

  int mt  = blockIdx.x >> 3;
  int nt  = blockIdx.x & 7;
  int tid = threadIdx.x;

  const unsigned short* Bb = BTh + (size_t)nt*128*DD;

  int w = tid >> 6, lane = tid & 63, l15 = lane & 15, l4 = lane >> 4;
  int wm = w >> 1, wn = w & 1;

  f32x4 zero4 = {0.0f, 0.0f, 0.0f, 0.0f};
  f32x4 acc[4][4];
#pragma unroll
  for (int i = 0; i < 4; ++i)
#pragma unroll
    for (int j = 0; j < 4; ++j) acc[i][j] = zero4;

  for (int kt = 0; kt < 4; ++kt){
    __syncthreads();
#pragma unroll
    for (int i = 0; i < 4; ++i){
      int ch = tid + i*256;
      int r = ch >> 3, c8 = ch & 7;
      int bb = r >> 3, ti = r & 7;
      int tx = xstart + mt*8 + ti;
      *(uint4*)(sA + r*72 + c8*8) = *(const uint4*)(Ah + ((size_t)bb*TT + tx)*DD + kt*64 + c8*8);
      *(uint4*)(sB + r*72 + c8*8) = *(const uint4*)(Bb + (size_t)r*DD + kt*64 + c8*8);
    }
    __syncthreads();
#pragma unroll
    for (int ks = 0; ks < 2; ++ks){
      short8 a[4], b[4];
#pragma unroll
      for (int mf = 0; mf < 4; ++mf)
        a[mf] = *(const short8*)(sA + (wm*64 + mf*16 + l15)*72 + ks*32 + l4*8);
#pragma unroll
      for (int nf = 0; nf < 4; ++nf)
        b[nf] = *(const short8*)(sB + (wn*64 + nf*16 + l15)*72 + ks*32 + l4*8);
#pragma unroll
      for (int mf = 0; mf < 4; ++mf)
#pragma unroll
        for (int nf = 0; nf < 4; ++nf)
          acc[mf][nf] = __builtin_amdgcn_mfma_f32_16x16x32_bf16(a[mf], b[nf], acc[mf][nf], 0, 0, 0);
    }
  }
  __syncthreads();
#pragma unroll
  for (int mf = 0; mf < 4; ++mf)
#pragma unroll
    for (int nf = 0; nf < 4; ++nf)
#pragma unroll
      for (int r = 0; r < 4; ++r)
        sC[(wm*64 + mf*16 + l4*4 + r)*136 + wn*64 + nf*16 + l15] = f2h_u(acc[mf][nf][r]);
  __syncthreads();
  int c = tid >> 1, half = tid & 1;
#pragma unroll
  for (int ti = 0; ti < 8; ++ti){
    unsigned short* slab = Cd + ((size_t)(mt*8 + ti)*GG + nt*128)*16;
    unsigned short v[8];
#pragma unroll
    for (int j = 0; j < 8; ++j)
      v[j] = sC[((half*8 + j)*8 + ti)*136 + c];
    uint4 pk;
    pk.x = (unsigned int)v[0] | ((unsigned int)v[1] << 16);
    pk.y = (unsigned int)v[2] | ((unsigned int)v[3] << 16);
    pk.z = (unsigned int)v[4] | ((unsigned int)v[5] << 16);
    pk.w = (unsigned int)v[6] | ((unsigned int)v[7] << 16);
    *(uint4*)(slab + c*16 + half*8) = pk;
  }
}

// ---- MFMA LSTM scan: A=R(regs), B=h(LDS), lane-local epilogue --------------
// 8 blocks/dir (32 units each), 8 waves/block (2/SIMD TLP). Wave w = M-tile
// (units 4w..4w+3 x 4 gates). hT layout: [uq 64][batch 17-pad][4 units].
// Sync: per-wave export drain (vmcnt(1)) + lane0 atomicAdd(flag,1);
// importer polls flag >= 8*s (all 8 waves of partner done). Barriers are
// LDS-only (B1: imports vs 7-slice reads; B3: region-Q write vs next own-read
// AND 7-slice reads vs next import lands). B2 dropped (R11-validated).
template<int Q>
__device__ __forceinline__ void scan_body(
    unsigned short* hT,                        // [64*68] shorts
    const unsigned short* __restrict__ projT,  // [2][Tc][1024][16] f16
    const unsigned short* __restrict__ rt,     // [2][1024][256] f16 (permuted)
    const float* __restrict__ bcf, const float* __restrict__ bcb,
    float* __restrict__ out,
    float* __restrict__ stH, float* __restrict__ stC,
    unsigned short* __restrict__ xchg,         // [2 d][2 slot][8 Q][512] shorts
    int* __restrict__ flags,                   // [16][32] int (counter per block)
    int t0, int t1, int Tc, int first, int d)
{
  int tid = threadIdx.x;
  int w = tid >> 6, l = tid & 63, l15 = l & 15, l4 = l >> 4;

  // ---- A-fragments (R), 8 slices x b128 = 32 VGPR, register-pinned ----
  u32x4 frag[8];
  {
    const unsigned short* Rd = rt + (size_t)d*262144
                             + ((size_t)(Q*128 + w*16 + l15))*256 + l4*8;
#pragma unroll
    for (int s = 0; s < 8; ++s)
      frag[s] = *(const u32x4*)(Rd + s*32);
  }
#pragma unroll
  for (int s = 0; s < 8; ++s)
    asm volatile("" : "+v"(frag[s]));

  // ---- init hT (all 256 units x 16 batches) ----
  const float* stHb = stH + d*4096;
  for (int idx = tid; idx < 4096; idx += 512){
    int b = idx >> 8, u = idx & 255;
    hT[(u >> 2)*68 + b*4 + (u & 3)] = first ? (unsigned short)0
                                            : f2h_u(stHb[b*256 + u]);
  }

  const int u_loc = 4*w + l4, u_g = 32*Q + u_loc;
  float c_r = 0.f, h_r = 0.f;
  if (!first) c_r = stC[(d*16 + l15)*256 + u_g];
  float bc_r = (d ? bcb : bcf)[u_g];

  const unsigned short* prj = projT + (size_t)d*Tc*16384;
  const int myflag = (d*8 + Q)*32;
  const int p = (Q + w) & 7;                  // import partner (waves 1..7)
  const int paflag = (d*8 + p)*32;
  const unsigned long long* xull = (const unsigned long long*)xchg;
  const int Tl = t1 - t0;

  __syncthreads();

  for (int s = 0; s < Tl; ++s){
    int t = t0 + s;
    int ps = d ? (Tl - 1 - s) : s;

    // proj: 4 b16 loads (consumed in epilogue; latency hidden)
    const unsigned short* pr = prj + (size_t)ps*16384;
    unsigned short pj0 = pr[(0*256 + u_g)*16 + l15];
    unsigned short pj1 = pr[(1*256 + u_g)*16 + l15];
    unsigned short pj2 = pr[(2*256 + u_g)*16 + l15];
    unsigned short pj3 = pr[(3*256 + u_g)*16 + l15];

    // own slice first (region Q, sealed by last step's B3) — overlaps poll
    f32x4 acc = {0.f, 0.f, 0.f, 0.f};
    {
      uint2 b0 = *(const uint2*)&hT[(Q*8     + l4)*68 + l15*4];
      uint2 b1 = *(const uint2*)&hT[(Q*8 + 4 + l4)*68 + l15*4];
      u32x4 bv = {b0.x, b0.y, b1.x, b1.y};
      acc = mfma16x16x32_f16(__builtin_bit_cast(f16x8, frag[Q]),
                             __builtin_bit_cast(f16x8, bv), acc);
    }

    // import partner slab (waves 1..7): busy-poll counter, 2 ull loads, land
    if (s > 0 && w >= 1){
      const int target = 8*s;
      while (__hip_atomic_load(&flags[paflag], __ATOMIC_RELAXED, __HIP_MEMORY_SCOPE_AGENT) < target)
        ;
      asm volatile("" ::: "memory");          // pin import loads after poll
      size_t base = (((size_t)d*2 + ((s - 1) & 1))*8 + p)*128;
      unsigned long long v0 = __hip_atomic_load(&xull[base + 2*l    ], __ATOMIC_RELAXED, __HIP_MEMORY_SCOPE_AGENT);
      unsigned long long v1 = __hip_atomic_load(&xull[base + 2*l + 1], __ATOMIC_RELAXED, __HIP_MEMORY_SCOPE_AGENT);
      int uq = 8*p + (l >> 3), bq = 2*(l & 7);
      *(uint2*)&hT[uq*68 + bq*4    ] = make_uint2((unsigned)v0, (unsigned)(v0 >> 32));
      *(uint2*)&hT[uq*68 + bq*4 + 4] = make_uint2((unsigned)v1, (unsigned)(v1 >> 32));
    }
    lds_barrier();                            // B1: imports visible (LDS only)

    // remaining 7 slices (compile-time frag index via template Q)
#pragma unroll
    for (int j = 1; j < 8; ++j){
      const int sg = (Q + j) & 7;
      uint2 b0 = *(const uint2*)&hT[(sg*8     + l4)*68 + l15*4];
      uint2 b1 = *(const uint2*)&hT[(sg*8 + 4 + l4)*68 + l15*4];
      u32x4 bv = {b0.x, b0.y, b1.x, b1.y};
      acc = mfma16x16x32_f16(__builtin_bit_cast(f16x8, frag[sg]),
                             __builtin_bit_cast(f16x8, bv), acc);
    }
    // (no B2: epilogue writes region Q only; nothing reads Q until after B3)

    // ---- lane-local epilogue: 1 state (unit u_g, batch l15) ----
    float gi = acc[0] + h2f(pj0);
    float gf = acc[1] + h2f(pj1);
    float go = acc[2] + h2f(pj2);
    float gc = acc[3] + h2f(pj3) + bc_r;
    float ig = sigmoid_f(gi);
    float fg = sigmoid_f(gf);
    float og = sigmoid_f(go);
    float cand = tanh_f(gc);
    c_r = sigmoid_f(fg*c_r + ig*cand);        // faithful quirk
    float h = tanh_f(c_r) * og;               // faithful quirk
    h_r = h;

    unsigned short hu = f2h_u(h);
    hT[(8*Q + w)*68 + l15*4 + l4] = hu;       // own region, read next step
    // export FIRST (vm store #1)...
    xchg[((size_t)(d*2 + (s & 1))*8 + Q)*512 + w*64 + l15*4 + l4] = hu;
    __builtin_amdgcn_sched_barrier(0);        // pin issue order: export before out
    // ...then out store (vm store #2, stays in flight past flag+barrier)
    out[((size_t)l15*TT + t)*512 + d*256 + u_g] = h;
    __builtin_amdgcn_sched_barrier(0);
    // per-wave: drain own export (FIFO: vmcnt(1) leaves only out-store), signal
    asm volatile("s_waitcnt vmcnt(1)" ::: "memory");
    if (l == 0)
      __hip_atomic_fetch_add(&flags[myflag], 1, __ATOMIC_RELAXED, __HIP_MEMORY_SCOPE_AGENT);
    lds_barrier();                            // B3: LDS-only (no vmcnt drain)
  }

  // chunk-carry state
  stC[(d*16 + l15)*256 + u_g] = c_r;
  stH[(d*16 + l15)*256 + u_g] = h_r;
}

__global__ __attribute__((amdgpu_flat_work_group_size(512, 512), amdgpu_waves_per_eu(2, 2)))
void lstm_scan_mfma(const unsigned short* __restrict__ projT,
                    const unsigned short* __restrict__ rt,
                    const float* __restrict__ bcf, const float* __restrict__ bcb,
                    float* __restrict__ out,
                    float* __restrict__ stH, float* __restrict__ stC,
                    unsigned short* __restrict__ xchg,
                    int* __restrict__ flags,
                    int t0, int t1, int Tc, int first)
{
  __shared__ __align__(16) unsigned short hT[64*68];   // 8704 B
  int blk = blockIdx.x;
  int d = blk & 7, Q = blk >> 3;                       // dir d pinned to XCD d
  if (d >= 2) return;
  switch (Q){
    case 0: scan_body<0>(hT, projT, rt, bcf, bcb, out, stH, stC, xchg, flags, t0, t1, Tc, first, d); break;
    case 1: scan_body<1>(hT, projT, rt, bcf, bcb, out, stH, stC, xchg, flags, t0, t1, Tc, first, d); break;
    case 2: scan_body<2>(hT, projT, rt, bcf, bcb, out, stH, stC, xchg, flags, t0, t1, Tc, first, d); break;
    case 3: scan_body<3>(hT, projT, rt, bcf, bcb, out, stH, stC, xchg, flags, t0, t1, Tc, first, d); break;
    case 4: scan_body<4>(hT, projT, rt, bcf, bcb, out, stH, stC, xchg, flags, t0, t1, Tc, first, d); break;
    case 5: scan_body<5>(hT, projT, rt, bcf, bcb, out, stH, stC, xchg, flags, t0, t1, Tc, first, d); break;
    case 6: scan_body<6>(hT, projT, rt, bcf, bcb, out, stH, stC, xchg, flags, t0, t1, Tc, first, d); break;
    default: scan_body<7>(hT, projT, rt, bcf, bcb, out, stH, stC, xchg, flags, t0, t1, Tc, first, d); break;
  }
}

// ---- launcher -------------------------------------------------------------
extern "C" void kernel_launch(void* const* d_in, const int* in_sizes, int n_in,
                              void* d_out, int out_size, void* d_ws, size_t ws_size,
                              hipStream_t stream){
  const float* x   = (const float*)d_in[0];
  const float* Wf  = (const float*)d_in[1];
  const float* Rf  = (const float*)d_in[2];
  const float* bcf = (const float*)d_in[3];
  const float* Wb  = (const float*)d_in[4];
  const float* Rb  = (const float*)d_in[5];
  const float* bcb = (const float*)d_in[6];
  float* out = (float*)d_out;
  char* ws = (char*)d_ws;

  const size_t OFF_XH    = 0;                        // 16 MiB: x bf16
  const size_t OFF_WT    = 16777216;                 // 1 MiB: W^T bf16 both dirs
  const size_t OFF_RT    = OFF_WT + 1048576;         // 1 MiB: R frags f16 both dirs
  const size_t OFF_STH   = OFF_RT + 1048576;         // 32 KiB h state
  const size_t OFF_STC   = OFF_STH + 32768;          // 32 KiB c state
  const size_t OFF_XCHG  = OFF_STC + 32768;          // 32 KiB h exchange
  const size_t OFF_FLAGS = OFF_XCHG + 32768;         // 4 KiB flags
  const size_t OFF_PROJT = OFF_FLAGS + 4096;         // projT chunk buffer

  unsigned short* xh    = (unsigned short*)(ws + OFF_XH);
  unsigned short* wt    = (unsigned short*)(ws + OFF_WT);
  unsigned short* rt    = (unsigned short*)(ws + OFF_RT);
  float*          stH   = (float*)(ws + OFF_STH);
  float*          stC   = (float*)(ws + OFF_STC);
  unsigned short* xchg  = (unsigned short*)(ws + OFF_XCHG);
  int*            flags = (int*)(ws + OFF_FLAGS);
  unsigned short* projT = (unsigned short*)(ws + OFF_PROJT);

  int Tc = TT;  // time-chunk; shrink if ws too small (projT = 65536*Tc bytes)
  while (Tc > 128 && OFF_PROJT + (size_t)65536*Tc > ws_size) Tc >>= 1;

  cvt_x_kernel<<<8192, 256, 0, stream>>>(x, xh);
  cvt_wt_kernel<<<2048, 256, 0, stream>>>(Wf, Wb, wt);
  cvt_rt_kernel<<<2048, 256, 0, stream>>>(Rf, Rb, rt);

  int nch = TT / Tc;
  for (int ch = 0; ch < nch; ++ch){
    int t0 = ch*Tc, t1 = t0 + Tc;
    gemm_projT<<<Tc, 256, 0, stream>>>(xh, wt,          projT,                     t0,      Tc);
    gemm_projT<<<Tc, 256, 0, stream>>>(xh, wt + 262144, projT + (size_t)Tc*GG*16,  TT - t1, Tc);
    hipMemsetAsync(flags, 0, 2048, stream);
    lstm_scan_mfma<<<64, 512, 0, stream>>>(projT, rt, bcf, bcb, out, stH, stC, xchg, flags,
                                           t0, t1, Tc, ch == 0 ? 1 : 0);
  }
}

// Round 13
// 3459.845 us; speedup vs baseline: 1.1483x; 1.1483x over previous
//
#include <hip/hip_runtime.h>
#include <hip/hip_bf16.h>
#include <hip/hip_fp16.h>

#define TT 2048
#define BB 16
#define DD 256
#define GG 1024   // 4U
#define UU 256

using f32x4  = __attribute__((ext_vector_type(4))) float;
using short8 = __attribute__((ext_vector_type(8))) short;
using f16x8  = __attribute__((ext_vector_type(8))) _Float16;
using u32x4  = __attribute__((ext_vector_type(4))) unsigned int;

static __device__ __forceinline__ unsigned short f2h_u(float f){
  _Float16 h = (_Float16)f;
  return __builtin_bit_cast(unsigned short, h);
}
static __device__ __forceinline__ float h2f(unsigned short u){
  return (float)__builtin_bit_cast(_Float16, u);
}
static __device__ __forceinline__ unsigned short f2bf_u(float f){
  __hip_bfloat16 b = __float2bfloat16(f);
  return __builtin_bit_cast(unsigned short, b);
}
static __device__ __forceinline__ float sigmoid_f(float x){
  return 1.0f / (1.0f + __expf(-x));
}
static __device__ __forceinline__ float tanh_f(float x){
  float ax = fabsf(x);
  float e  = __expf(2.0f*ax);          // overflow -> inf is fine: r -> 1
  float r  = 1.0f - 2.0f/(e + 1.0f);
  return copysignf(r, x);
}
static __device__ __forceinline__ f32x4 mfma16x16x32_f16(f16x8 a, f16x8 b, f32x4 c){
  return __builtin_amdgcn_mfma_f32_16x16x32_f16(a, b, c, 0, 0, 0);
}
// raw workgroup barrier ordering LDS only (no vmcnt drain)
static __device__ __forceinline__ void lds_barrier(){
  __builtin_amdgcn_sched_barrier(0);
  asm volatile("s_waitcnt lgkmcnt(0)" ::: "memory");
  __builtin_amdgcn_s_barrier();
  __builtin_amdgcn_sched_barrier(0);
}

// ---- converts -------------------------------------------------------------
__global__ __launch_bounds__(256) void cvt_x_kernel(const float* __restrict__ x,
                                                    unsigned short* __restrict__ xh){
  int gid = blockIdx.x*256 + threadIdx.x;
  const float4* xv = (const float4*)x;
  float4 v = xv[gid];
  unsigned int u0 = (unsigned int)f2bf_u(v.x) | ((unsigned int)f2bf_u(v.y) << 16);
  unsigned int u1 = (unsigned int)f2bf_u(v.z) | ((unsigned int)f2bf_u(v.w) << 16);
  ((uint2*)xh)[gid] = make_uint2(u0, u1);
}

// W [256][1024] f32 -> W^T bf16 [dir][1024][256]
__global__ __launch_bounds__(256) void cvt_wt_kernel(const float* __restrict__ Wf,
                                                     const float* __restrict__ Wb,
                                                     unsigned short* __restrict__ wt){
  int gid = blockIdx.x*256 + threadIdx.x;
  int d   = gid >> 18;
  int rem = gid & 262143;
  int n   = rem >> 8;
  int k   = rem & 255;
  const float* src = d ? Wb : Wf;
  wt[gid] = f2bf_u(src[k*GG + n]);
}

// R [256][1024] f32 -> A-fragment-ready f16, col-order [block Q][unit][gate],
// k-permuted to match the scan's h^T B-fragment assembly:
//   storage pos p (0..255): s=p>>5, l4=(p>>3)&3, e=p&7
//   k = 32s + (e<4 ? 4*l4+e : 16 + 4*l4 + (e-4))
__global__ __launch_bounds__(256) void cvt_rt_kernel(const float* __restrict__ Rf,
                                                     const float* __restrict__ Rb,
                                                     unsigned short* __restrict__ rt){
  int gid = blockIdx.x*256 + threadIdx.x;           // 2*1024*256
  int d   = gid >> 18;
  int rem = gid & 262143;
  int c   = rem >> 8;                               // storage col 0..1023
  int p   = rem & 255;                              // k-position
  int Qb  = c >> 7, tc = c & 127;
  int ul  = tc >> 2, g = tc & 3;
  int ucol = g*256 + Qb*32 + ul;                    // source col in R[256][1024]
  int s = p >> 5, l4g = (p >> 3) & 3, e = p & 7;
  int k = 32*s + (e < 4 ? 4*l4g + e : 16 + 4*l4g + (e - 4));
  const float* src = d ? Rb : Rf;
  rt[gid] = f2h_u(src[k*GG + ucol]);
}

// ---- proj GEMM: M-tile = 16 batches x 8 timesteps; writes projT[t][col][16b]
__global__ __launch_bounds__(256) void gemm_projT(const unsigned short* __restrict__ Ah,
                                                  const unsigned short* __restrict__ BTh,
                                                  unsigned short* __restrict__ Cd,
                                                  int xstart, int Tc){
  __shared__ __align__(16) unsigned short smem[18432];
  unsigned short* sA = smem;             // [128][72]
  unsigned short* sB = smem + 9216;      // [128][72]
  unsigned short* sC = smem;             // [128][136]

  int mt  = blockIdx.x >> 3;
  int nt  = blockIdx.x & 7;
  int tid = threadIdx.x;

  const unsigned short* Bb = BTh + (size_t)nt*128*DD;

  int w = tid >> 6, lane = tid & 63, l15 = lane & 15, l4 = lane >> 4;
  int wm = w >> 1, wn = w & 1;

  f32x4 zero4 = {0.0f, 0.0f, 0.0f, 0.0f};
  f32x4 acc[4][4];
#pragma unroll
  for (int i = 0; i < 4; ++i)
#pragma unroll
    for (int j = 0; j < 4; ++j) acc[i][j] = zero4;

  for (int kt = 0; kt < 4; ++kt){
    __syncthreads();
#pragma unroll
    for (int i = 0; i < 4; ++i){
      int ch = tid + i*256;
      int r = ch >> 3, c8 = ch & 7;
      int bb = r >> 3, ti = r & 7;
      int tx = xstart + mt*8 + ti;
      *(uint4*)(sA + r*72 + c8*8) = *(const uint4*)(Ah + ((size_t)bb*TT + tx)*DD + kt*64 + c8*8);
      *(uint4*)(sB + r*72 + c8*8) = *(const uint4*)(Bb + (size_t)r*DD + kt*64 + c8*8);
    }
    __syncthreads();
#pragma unroll
    for (int ks = 0; ks < 2; ++ks){
      short8 a[4], b[4];
#pragma unroll
      for (int mf = 0; mf < 4; ++mf)
        a[mf] = *(const short8*)(sA + (wm*64 + mf*16 + l15)*72 + ks*32 + l4*8);
#pragma unroll
      for (int nf = 0; nf < 4; ++nf)
        b[nf] = *(const short8*)(sB + (wn*64 + nf*16 + l15)*72 + ks*32 + l4*8);
#pragma unroll
      for (int mf = 0; mf < 4; ++mf)
#pragma unroll
        for (int nf = 0; nf < 4; ++nf)
          acc[mf][nf] = __builtin_amdgcn_mfma_f32_16x16x32_bf16(a[mf], b[nf], acc[mf][nf], 0, 0, 0);
    }
  }
  __syncthreads();
#pragma unroll
  for (int mf = 0; mf < 4; ++mf)
#pragma unroll
    for (int nf = 0; nf < 4; ++nf)
#pragma unroll
      for (int r = 0; r < 4; ++r)
        sC[(wm*64 + mf*16 + l4*4 + r)*136 + wn*64 + nf*16 + l15] = f2h_u(acc[mf][nf][r]);
  __syncthreads();
  int c = tid >> 1, half = tid & 1;
#pragma unroll
  for (int ti = 0; ti < 8; ++ti){
    unsigned short* slab = Cd + ((size_t)(mt*8 + ti)*GG + nt*128)*16;
    unsigned short v[8];
#pragma unroll
    for (int j = 0; j < 8; ++j)
      v[j] = sC[((half*8 + j)*8 + ti)*136 + c];
    uint4 pk;
    pk.x = (unsigned int)v[0] | ((unsigned int)v[1] << 16);
    pk.y = (unsigned int)v[2] | ((unsigned int)v[3] << 16);
    pk.z = (unsigned int)v[4] | ((unsigned int)v[5] << 16);
    pk.w = (unsigned int)v[6] | ((unsigned int)v[7] << 16);
    *(uint4*)(slab + c*16 + half*8) = pk;
  }
}

// ---- MFMA LSTM scan: A=R(regs), B=h(LDS), lane-local epilogue --------------
// 8 blocks/dir (32 units each), 8 waves (2/SIMD TLP). Wave w = M-tile
// (units 4w..4w+3 x 4 gates). hT layout: [uq 64][batch][4 units], 68/row.
// R10 protocol, minus barrier B2 (validated R11/R12):
//   hazards: (import lands, 7-slice reads) -> B1;
//            (epilogue region-Q write, next-step own-reads) -> B3.
//   Post-B1 slice reads touch regions != Q only; epilogue writes region Q
//   only; pre-B1 own-reads can't race epilogue (no wave passes B1 early).
template<int Q>
__device__ __forceinline__ void scan_body(
    unsigned short* hT,                        // [64*68] shorts
    const unsigned short* __restrict__ projT,  // [2][Tc][1024][16] f16
    const unsigned short* __restrict__ rt,     // [2][1024][256] f16 (permuted)
    const float* __restrict__ bcf, const float* __restrict__ bcb,
    float* __restrict__ out,
    float* __restrict__ stH, float* __restrict__ stC,
    unsigned short* __restrict__ xchg,         // [2 d][2 slot][8 Q][512] shorts
    int* __restrict__ flags,                   // [16][32] int
    int t0, int t1, int Tc, int first, int d)
{
  int tid = threadIdx.x;
  int w = tid >> 6, l = tid & 63, l15 = l & 15, l4 = l >> 4;

  // ---- A-fragments (R), 8 slices x b128 = 32 VGPR, register-pinned ----
  u32x4 frag[8];
  {
    const unsigned short* Rd = rt + (size_t)d*262144
                             + ((size_t)(Q*128 + w*16 + l15))*256 + l4*8;
#pragma unroll
    for (int s = 0; s < 8; ++s)
      frag[s] = *(const u32x4*)(Rd + s*32);
  }
#pragma unroll
  for (int s = 0; s < 8; ++s)
    asm volatile("" : "+v"(frag[s]));

  // ---- init hT (all 256 units x 16 batches) ----
  const float* stHb = stH + d*4096;
  for (int idx = tid; idx < 4096; idx += 512){
    int b = idx >> 8, u = idx & 255;
    hT[(u >> 2)*68 + b*4 + (u & 3)] = first ? (unsigned short)0
                                            : f2h_u(stHb[b*256 + u]);
  }

  const int u_loc = 4*w + l4, u_g = 32*Q + u_loc;
  float c_r = 0.f, h_r = 0.f;
  if (!first) c_r = stC[(d*16 + l15)*256 + u_g];
  float bc_r = (d ? bcb : bcf)[u_g];

  const unsigned short* prj = projT + (size_t)d*Tc*16384;
  const int myflag = (d*8 + Q)*32;
  const int p = (Q + w) & 7;                  // import partner (waves 1..7)
  const int paflag = (d*8 + p)*32;
  const unsigned long long* xull = (const unsigned long long*)xchg;
  const int Tl = t1 - t0;

  __syncthreads();

  for (int s = 0; s < Tl; ++s){
    int t = t0 + s;
    int ps = d ? (Tl - 1 - s) : s;

    // proj: 4 b16 loads (consumed in epilogue; latency hidden)
    const unsigned short* pr = prj + (size_t)ps*16384;
    unsigned short pj0 = pr[(0*256 + u_g)*16 + l15];
    unsigned short pj1 = pr[(1*256 + u_g)*16 + l15];
    unsigned short pj2 = pr[(2*256 + u_g)*16 + l15];
    unsigned short pj3 = pr[(3*256 + u_g)*16 + l15];

    // import partner slab (waves 1..7): poll + 2 ull atomic loads
    unsigned long long v0 = 0, v1 = 0;
    if (s > 0 && w >= 1){
      while (__hip_atomic_load(&flags[paflag], __ATOMIC_RELAXED, __HIP_MEMORY_SCOPE_AGENT) < s)
        __builtin_amdgcn_s_sleep(1);
      size_t base = (((size_t)d*2 + ((s - 1) & 1))*8 + p)*128;
      v0 = __hip_atomic_load(&xull[base + 2*l    ], __ATOMIC_RELAXED, __HIP_MEMORY_SCOPE_AGENT);
      v1 = __hip_atomic_load(&xull[base + 2*l + 1], __ATOMIC_RELAXED, __HIP_MEMORY_SCOPE_AGENT);
    }

    // own slice (units 32Q..32Q+31, written locally last step) before B1;
    // runs while the import loads above are in flight
    f32x4 acc = {0.f, 0.f, 0.f, 0.f};
    {
      uint2 b0 = *(const uint2*)&hT[(Q*8     + l4)*68 + l15*4];
      uint2 b1 = *(const uint2*)&hT[(Q*8 + 4 + l4)*68 + l15*4];
      u32x4 bv = {b0.x, b0.y, b1.x, b1.y};
      acc = mfma16x16x32_f16(__builtin_bit_cast(f16x8, frag[Q]),
                             __builtin_bit_cast(f16x8, bv), acc);
    }

    // land imports (contiguous 2 x b64 per lane)
    if (s > 0 && w >= 1){
      int uq = 8*p + (l >> 3), bq = 2*(l & 7);
      *(uint2*)&hT[uq*68 + bq*4    ] = make_uint2((unsigned)v0, (unsigned)(v0 >> 32));
      *(uint2*)&hT[uq*68 + bq*4 + 4] = make_uint2((unsigned)v1, (unsigned)(v1 >> 32));
    }
    lds_barrier();                            // B1: imports visible (LDS only)

    // remaining 7 slices (compile-time frag index via template Q)
#pragma unroll
    for (int j = 1; j < 8; ++j){
      const int sg = (Q + j) & 7;
      uint2 b0 = *(const uint2*)&hT[(sg*8     + l4)*68 + l15*4];
      uint2 b1 = *(const uint2*)&hT[(sg*8 + 4 + l4)*68 + l15*4];
      u32x4 bv = {b0.x, b0.y, b1.x, b1.y};
      acc = mfma16x16x32_f16(__builtin_bit_cast(f16x8, frag[sg]),
                             __builtin_bit_cast(f16x8, bv), acc);
    }
    // (no B2: epilogue writes region Q only; post-B1 reads touch regions != Q;
    //  pre-B1 own-reads can't race epilogue because B1 gates all waves)

    // ---- lane-local epilogue: 1 state (unit u_g, batch l15) ----
    float gi = acc[0] + h2f(pj0);
    float gf = acc[1] + h2f(pj1);
    float go = acc[2] + h2f(pj2);
    float gc = acc[3] + h2f(pj3) + bc_r;
    float ig = sigmoid_f(gi);
    float fg = sigmoid_f(gf);
    float og = sigmoid_f(go);
    float cand = tanh_f(gc);
    c_r = sigmoid_f(fg*c_r + ig*cand);        // faithful quirk
    float h = tanh_f(c_r) * og;               // faithful quirk
    h_r = h;

    unsigned short hu = f2h_u(h);
    hT[(8*Q + w)*68 + l15*4 + l4] = hu;       // own region, read next step
    // export FIRST (vm store #1)...
    xchg[((size_t)(d*2 + (s & 1))*8 + Q)*512 + w*64 + l15*4 + l4] = hu;
    __builtin_amdgcn_sched_barrier(0);        // pin issue order: export before out
    // ...then out store (vm store #2, stays in flight past barrier+flag)
    out[((size_t)l15*TT + t)*512 + d*256 + u_g] = h;
    __builtin_amdgcn_sched_barrier(0);
    // B3: export drained (vmcnt FIFO: <=1 outstanding leaves only out-store),
    //     hT writes ordered; out-store NOT waited.
    asm volatile("s_waitcnt vmcnt(1) lgkmcnt(0)" ::: "memory");
    __builtin_amdgcn_s_barrier();
    __builtin_amdgcn_sched_barrier(0);
    if (tid == 0)
      __hip_atomic_store(&flags[myflag], s + 1, __ATOMIC_RELAXED, __HIP_MEMORY_SCOPE_AGENT);
  }

  // chunk-carry state
  stC[(d*16 + l15)*256 + u_g] = c_r;
  stH[(d*16 + l15)*256 + u_g] = h_r;
}

__global__ __attribute__((amdgpu_flat_work_group_size(512, 512), amdgpu_waves_per_eu(2, 2)))
void lstm_scan_mfma(const unsigned short* __restrict__ projT,
                    const unsigned short* __restrict__ rt,
                    const float* __restrict__ bcf, const float* __restrict__ bcb,
                    float* __restrict__ out,
                    float* __restrict__ stH, float* __restrict__ stC,
                    unsigned short* __restrict__ xchg,
                    int* __restrict__ flags,
                    int t0, int t1, int Tc, int first)
{
  __shared__ __align__(16) unsigned short hT[64*68];   // 8704 B
  int blk = blockIdx.x;
  int d = blk & 7, Q = blk >> 3;                       // dir d pinned to XCD d
  if (d >= 2) return;
  switch (Q){
    case 0: scan_body<0>(hT, projT, rt, bcf, bcb, out, stH, stC, xchg, flags, t0, t1, Tc, first, d); break;
    case 1: scan_body<1>(hT, projT, rt, bcf, bcb, out, stH, stC, xchg, flags, t0, t1, Tc, first, d); break;
    case 2: scan_body<2>(hT, projT, rt, bcf, bcb, out, stH, stC, xchg, flags, t0, t1, Tc, first, d); break;
    case 3: scan_body<3>(hT, projT, rt, bcf, bcb, out, stH, stC, xchg, flags, t0, t1, Tc, first, d); break;
    case 4: scan_body<4>(hT, projT, rt, bcf, bcb, out, stH, stC, xchg, flags, t0, t1, Tc, first, d); break;
    case 5: scan_body<5>(hT, projT, rt, bcf, bcb, out, stH, stC, xchg, flags, t0, t1, Tc, first, d); break;
    case 6: scan_body<6>(hT, projT, rt, bcf, bcb, out, stH, stC, xchg, flags, t0, t1, Tc, first, d); break;
    default: scan_body<7>(hT, projT, rt, bcf, bcb, out, stH, stC, xchg, flags, t0, t1, Tc, first, d); break;
  }
}

// ---- launcher -------------------------------------------------------------
extern "C" void kernel_launch(void* const* d_in, const int* in_sizes, int n_in,
                              void* d_out, int out_size, void* d_ws, size_t ws_size,
                              hipStream_t stream){
  const float* x   = (const float*)d_in[0];
  const float* Wf  = (const float*)d_in[1];
  const float* Rf  = (const float*)d_in[2];
  const float* bcf = (const float*)d_in[3];
  const float* Wb  = (const float*)d_in[4];
  const float* Rb  = (const float*)d_in[5];
  const float* bcb = (const float*)d_in[6];
  float* out = (float*)d_out;
  char* ws = (char*)d_ws;

  const size_t OFF_XH    = 0;                        // 16 MiB: x bf16
  const size_t OFF_WT    = 16777216;                 // 1 MiB: W^T bf16 both dirs
  const size_t OFF_RT    = OFF_WT + 1048576;         // 1 MiB: R frags f16 both dirs
  const size_t OFF_STH   = OFF_RT + 1048576;         // 32 KiB h state
  const size_t OFF_STC   = OFF_STH + 32768;          // 32 KiB c state
  const size_t OFF_XCHG  = OFF_STC + 32768;          // 32 KiB h exchange
  const size_t OFF_FLAGS = OFF_XCHG + 32768;         // 4 KiB flags
  const size_t OFF_PROJT = OFF_FLAGS + 4096;         // projT chunk buffer

  unsigned short* xh    = (unsigned short*)(ws + OFF_XH);
  unsigned short* wt    = (unsigned short*)(ws + OFF_WT);
  unsigned short* rt    = (unsigned short*)(ws + OFF_RT);
  float*          stH   = (float*)(ws + OFF_STH);
  float*          stC   = (float*)(ws + OFF_STC);
  unsigned short* xchg  = (unsigned short*)(ws + OFF_XCHG);
  int*            flags = (int*)(ws + OFF_FLAGS);
  unsigned short* projT = (unsigned short*)(ws + OFF_PROJT);

  int Tc = TT;  // time-chunk; shrink if ws too small (projT = 65536*Tc bytes)
  while (Tc > 128 && OFF_PROJT + (size_t)65536*Tc > ws_size) Tc >>= 1;

  cvt_x_kernel<<<8192, 256, 0, stream>>>(x, xh);
  cvt_wt_kernel<<<2048, 256, 0, stream>>>(Wf, Wb, wt);
  cvt_rt_kernel<<<2048, 256, 0, stream>>>(Rf, Rb, rt);

  int nch = TT / Tc;
  for (int ch = 0; ch < nch; ++ch){
    int t0 = ch*Tc, t1 = t0 + Tc;
    gemm_projT<<<Tc, 256, 0, stream>>>(xh, wt,          projT,                     t0,      Tc);
    gemm_projT<<<Tc, 256, 0, stream>>>(xh, wt + 262144, projT + (size_t)Tc*GG*16,  TT - t1, Tc);
    hipMemsetAsync(flags, 0, 2048, stream);
    lstm_scan_mfma<<<64, 512, 0, stream>>>(projT, rt, bcf, bcb, out, stH, stC, xchg, flags,
                                           t0, t1, Tc, ch == 0 ? 1 : 0);
  }
}